// Round 1
// baseline (1092.968 us; speedup 1.0000x reference)
//
#include <hip/hip_runtime.h>
#include <math.h>

#define NDIM 256
#define VOL  (NDIM*NDIM*NDIM)      // 16777216 elements per batch-channel volume
#define NB   128                    // kept bins 0..127; label 128 is dropped

typedef float2 cplx;

__device__ __forceinline__ int br8(int x) { return (int)(__brev((unsigned)x) >> 24); }

// ---------------------------------------------------------------------------
// Pass 1: pack (ref + i*pred) and FFT along z (contiguous axis).
// One wave per 256-pt line, radix-2 Stockham in LDS, natural-order output.
// grid = 16384 blocks x 256 threads (4 lines/block).
// ---------------------------------------------------------------------------
__global__ __launch_bounds__(256) void fftz_pack(const float* __restrict__ re_in,
                                                 const float* __restrict__ im_in,
                                                 float2* __restrict__ out)
{
    __shared__ float2 buf[2][4][NDIM];   // 16 KB
    const int w = threadIdx.x >> 6, lane = threadIdx.x & 63;
    const int L = blockIdx.x * 4 + w;    // line id in [0, 65536)
    const float* rp = re_in + (size_t)L * NDIM;
    const float* ip = im_in + (size_t)L * NDIM;

    for (int r = 0; r < 4; ++r) {
        int k = lane + 64 * r;
        buf[0][w][k] = make_float2(rp[k], ip[k]);
    }
    __syncthreads();

    int p = 0;
    for (int st = 0; st < 8; ++st) {
        const int Ns = 1 << st;
        for (int h = 0; h < 2; ++h) {
            int j  = lane + 64 * h;              // butterfly id in [0,128)
            int jm = j & (Ns - 1);
            float2 v0 = buf[p][w][j];
            float2 v1 = buf[p][w][j + 128];
            float sn, cs;
            sincosf(-(float)M_PI * (float)jm / (float)Ns, &sn, &cs);
            float2 v1r = make_float2(v1.x * cs - v1.y * sn, v1.x * sn + v1.y * cs);
            int idxD = ((j >> st) << (st + 1)) + jm;
            buf[p ^ 1][w][idxD]      = make_float2(v0.x + v1r.x, v0.y + v1r.y);
            buf[p ^ 1][w][idxD + Ns] = make_float2(v0.x - v1r.x, v0.y - v1r.y);
        }
        __syncthreads();
        p ^= 1;
    }

    float2* op = out + (size_t)L * NDIM;
    for (int r = 0; r < 4; ++r) {
        int k = lane + 64 * r;
        op[k] = buf[p][w][k];
    }
}

// ---------------------------------------------------------------------------
// Passes 2/3: in-place DIF radix-2 FFT along a strided axis.
// Tile: 256 (FFT dim) x 16 (contiguous z) in LDS, ld padded 16->17.
// Output is bit-reversed along the transformed axis.
// y-pass: lineStride=256,   outerStride=65536  (outer index = x)
// x-pass: lineStride=65536, outerStride=256    (outer index = y)
// grid = 4096 blocks (256 outer x 16 z-chunks) x 256 threads.
// ---------------------------------------------------------------------------
__global__ __launch_bounds__(256) void fft_strided(float2* __restrict__ A,
                                                   int lineStride, int outerStride)
{
    __shared__ float2 tile[NDIM * 17];   // ~34.8 KB
    const int t = threadIdx.x;
    const int l = t & 15, u = t >> 4;
    const int o = blockIdx.x >> 4, c = blockIdx.x & 15;
    const long long base = (long long)o * outerStride + c * 16;

    for (int it = 0; it < 16; ++it) {
        int pos = u + it * 16;
        tile[pos * 17 + l] = A[base + (long long)pos * lineStride + l];
    }
    __syncthreads();

    for (int st = 7; st >= 0; --st) {
        const int s = 1 << st;
        for (int it = 0; it < 8; ++it) {
            int m  = u + (it << 4);            // butterfly id in [0,128)
            int jm = m & (s - 1);
            int i0 = ((m >> st) << (st + 1)) + jm;
            int i1 = i0 + s;
            float2 a0 = tile[i0 * 17 + l];
            float2 a1 = tile[i1 * 17 + l];
            tile[i0 * 17 + l] = make_float2(a0.x + a1.x, a0.y + a1.y);
            float dx = a0.x - a1.x, dy = a0.y - a1.y;
            float sn, cs;
            sincosf(-(float)M_PI * (float)jm / (float)s, &sn, &cs);
            tile[i1 * 17 + l] = make_float2(dx * cs - dy * sn, dx * sn + dy * cs);
        }
        __syncthreads();
    }

    for (int it = 0; it < 16; ++it) {
        int pos = u + it * 16;
        A[base + (long long)pos * lineStride + l] = tile[pos * 17 + l];
    }
}

// ---------------------------------------------------------------------------
// Pass 4: unpack F1/F2 from Z(k), Z(-k); shell-binned sums of cross/p1/p2.
// Axis orders: x,y bit-reversed (freq = br8(pos)), z natural.
// Elements with label >= 128 fall in the dropped bin -> skipped.
// grid = 4096 blocks (16 lines each) x 256 threads.  bins: [3][128] floats.
// ---------------------------------------------------------------------------
__global__ __launch_bounds__(256) void reduce_shells(const float2* __restrict__ A,
                                                     float* __restrict__ bins)
{
    __shared__ float bs[3 * NB];
    const int t = threadIdx.x;
    for (int i = t; i < 3 * NB; i += 256) bs[i] = 0.f;
    __syncthreads();

    const int pz  = t;
    const int izc = (pz < 128) ? pz : 256 - pz;
    const int iz2 = izc * izc;
    const int pzp = (256 - pz) & 255;

    for (int l = 0; l < 16; ++l) {
        int L  = blockIdx.x * 16 + l;
        int px = L >> 8, py = L & 255;
        int fx = br8(px), fy = br8(py);
        int ax = (fx < 128) ? fx : 256 - fx;
        int ay = (fy < 128) ? fy : 256 - fy;
        int m  = ax * ax + ay * ay + iz2;
        int lab = (int)sqrtf((float)m);
        if (lab >= NB) continue;                 // dropped trash bin

        int pxp = br8((256 - fx) & 255);
        int pyp = br8((256 - fy) & 255);
        float2 z1 = A[(long long)L * 256 + pz];
        float2 z2 = A[(long long)(pxp * 256 + pyp) * 256 + pzp];

        float F1r = 0.5f * (z1.x + z2.x);
        float F1i = 0.5f * (z1.y - z2.y);
        float F2r = 0.5f * (z1.y + z2.y);
        float F2i = 0.5f * (z2.x - z1.x);

        atomicAdd(&bs[lab],            F1r * F2r + F1i * F2i);  // cross
        atomicAdd(&bs[NB + lab],       F1r * F1r + F1i * F1i);  // p1
        atomicAdd(&bs[2 * NB + lab],   F2r * F2r + F2i * F2i);  // p2
    }
    __syncthreads();
    for (int i = t; i < 3 * NB; i += 256) atomicAdd(&bins[i], bs[i]);
}

// ---------------------------------------------------------------------------
__global__ void zero_bins(float* bins)
{
    int t = blockIdx.x * blockDim.x + threadIdx.x;
    if (t < 2 * 3 * NB) bins[t] = 0.f;
}

__global__ void finalize(const float* __restrict__ binsAll, float* __restrict__ out)
{
    __shared__ float red[256];
    const int t = threadIdx.x;
    const int b = t >> 7, bin = t & 127;
    const float* bb = binsAll + b * 3 * NB;
    float num = bb[bin], d1 = bb[NB + bin], d2 = bb[2 * NB + bin];
    float fsc = num / sqrtf(d1 * d2 + 1e-8f);
    red[t] = fsc * fsc;
    __syncthreads();
    for (int s = 128; s > 0; s >>= 1) {
        if (t < s) red[t] += red[t + s];
        __syncthreads();
    }
    if (t == 0) out[0] = 1.f - red[0] / 256.f;
}

__global__ void ws_too_small(float* out) { out[0] = -1.0e9f; }

// ---------------------------------------------------------------------------
extern "C" void kernel_launch(void* const* d_in, const int* in_sizes, int n_in,
                              void* d_out, int out_size, void* d_ws, size_t ws_size,
                              hipStream_t stream)
{
    const float* ref  = (const float*)d_in[0];
    const float* pred = (const float*)d_in[1];
    float* out = (float*)d_out;

    const size_t volBytes = (size_t)VOL * sizeof(float2);   // 134,217,728
    if (ws_size < volBytes + 4096) {
        ws_too_small<<<1, 1, 0, stream>>>(out);
        return;
    }
    float2* A   = (float2*)d_ws;
    float* bins = (float*)((char*)d_ws + volBytes);          // [2][3][128]

    zero_bins<<<1, 1024, 0, stream>>>(bins);

    for (int b = 0; b < 2; ++b) {
        fftz_pack  <<<16384, 256, 0, stream>>>(ref + (size_t)b * VOL,
                                               pred + (size_t)b * VOL, A);
        fft_strided<<<4096, 256, 0, stream>>>(A, 256,   65536);  // y-pass
        fft_strided<<<4096, 256, 0, stream>>>(A, 65536, 256);    // x-pass
        reduce_shells<<<4096, 256, 0, stream>>>(A, bins + b * 3 * NB);
    }
    finalize<<<1, 256, 0, stream>>>(bins, out);
}

// Round 2
// 969.518 us; speedup vs baseline: 1.1273x; 1.1273x over previous
//
#include <hip/hip_runtime.h>
#include <math.h>

#define NDIM 256
#define VOL  (NDIM*NDIM*NDIM)      // 16777216 elements per batch-channel volume
#define NB   128                    // kept bins 0..127; label 128 is dropped

__device__ __forceinline__ int br8(int x) { return (int)(__brev((unsigned)x) >> 24); }

// ---------------------------------------------------------------------------
// Pass 1: pack (ref + i*pred) and FFT along z (contiguous axis).
// One wave per 256-pt line, radix-2 Stockham in LDS, natural-order output.
// Twiddles from a 128-entry LDS table: angle(k) = -pi*k/128.
// ---------------------------------------------------------------------------
__global__ __launch_bounds__(256) void fftz_pack(const float* __restrict__ re_in,
                                                 const float* __restrict__ im_in,
                                                 float2* __restrict__ out)
{
    __shared__ float2 buf[2][4][NDIM];   // 16 KB
    __shared__ float2 tw[128];           // 1 KB
    const int t = threadIdx.x;
    const int w = t >> 6, lane = t & 63;
    const int L = blockIdx.x * 4 + w;    // line id in [0, 65536)
    const float* rp = re_in + (size_t)L * NDIM;
    const float* ip = im_in + (size_t)L * NDIM;

    if (t < 128) {
        float sn, cs;
        __sincosf(-(float)M_PI * (float)t / 128.0f, &sn, &cs);
        tw[t] = make_float2(cs, sn);
    }
    for (int r = 0; r < 4; ++r) {
        int k = lane + 64 * r;
        buf[0][w][k] = make_float2(rp[k], ip[k]);
    }
    __syncthreads();

    int p = 0;
    for (int st = 0; st < 8; ++st) {
        const int Ns = 1 << st;
        for (int h = 0; h < 2; ++h) {
            int j  = lane + 64 * h;              // butterfly id in [0,128)
            int jm = j & (Ns - 1);
            float2 v0 = buf[p][w][j];
            float2 v1 = buf[p][w][j + 128];
            float2 tt = tw[jm << (7 - st)];
            float2 v1r = make_float2(v1.x * tt.x - v1.y * tt.y,
                                     v1.x * tt.y + v1.y * tt.x);
            int idxD = ((j >> st) << (st + 1)) + jm;
            buf[p ^ 1][w][idxD]      = make_float2(v0.x + v1r.x, v0.y + v1r.y);
            buf[p ^ 1][w][idxD + Ns] = make_float2(v0.x - v1r.x, v0.y - v1r.y);
        }
        __syncthreads();
        p ^= 1;
    }

    float2* op = out + (size_t)L * NDIM;
    for (int r = 0; r < 4; ++r) {
        int k = lane + 64 * r;
        op[k] = buf[p][w][k];
    }
}

// ---------------------------------------------------------------------------
// Passes 2/3: in-place DIF radix-2 FFT along a strided axis.
// Tile: 256 (FFT dim) x 16 (contiguous z) in LDS, ld padded 16->17.
// Output bit-reversed along the transformed axis. Twiddle table as above.
// ---------------------------------------------------------------------------
__global__ __launch_bounds__(256) void fft_strided(float2* __restrict__ A,
                                                   int lineStride, int outerStride)
{
    __shared__ float2 tile[NDIM * 17];   // ~34.8 KB
    __shared__ float2 tw[128];
    const int t = threadIdx.x;
    const int l = t & 15, u = t >> 4;
    const int o = blockIdx.x >> 4, c = blockIdx.x & 15;
    const long long base = (long long)o * outerStride + c * 16;

    if (t < 128) {
        float sn, cs;
        __sincosf(-(float)M_PI * (float)t / 128.0f, &sn, &cs);
        tw[t] = make_float2(cs, sn);
    }
    for (int it = 0; it < 16; ++it) {
        int pos = u + it * 16;
        tile[pos * 17 + l] = A[base + (long long)pos * lineStride + l];
    }
    __syncthreads();

    for (int st = 7; st >= 0; --st) {
        const int s = 1 << st;
        for (int it = 0; it < 8; ++it) {
            int m  = u + (it << 4);            // butterfly id in [0,128)
            int jm = m & (s - 1);
            int i0 = ((m >> st) << (st + 1)) + jm;
            int i1 = i0 + s;
            float2 a0 = tile[i0 * 17 + l];
            float2 a1 = tile[i1 * 17 + l];
            tile[i0 * 17 + l] = make_float2(a0.x + a1.x, a0.y + a1.y);
            float dx = a0.x - a1.x, dy = a0.y - a1.y;
            float2 tt = tw[jm << (7 - st)];
            tile[i1 * 17 + l] = make_float2(dx * tt.x - dy * tt.y,
                                            dx * tt.y + dy * tt.x);
        }
        __syncthreads();
    }

    for (int it = 0; it < 16; ++it) {
        int pos = u + it * 16;
        A[base + (long long)pos * lineStride + l] = tile[pos * 17 + l];
    }
}

// ---------------------------------------------------------------------------
// Pass 4: unpack F1/F2 from Z(k), Z(-k); shell-binned sums of cross/p1/p2.
// grid = 1024 blocks, 64 interleaved lines each. Per-WAVE LDS histograms
// (no inter-wave LDS atomic contention); one flush of 384 global atomics
// per block (1024-deep per-address serialization, down from 4096-deep).
// ---------------------------------------------------------------------------
__global__ __launch_bounds__(256) void reduce_shells(const float2* __restrict__ A,
                                                     float* __restrict__ bins)
{
    __shared__ float bs[4][3 * NB];      // 6 KB, one histogram per wave
    const int t = threadIdx.x;
    const int w = t >> 6;
    for (int i = t; i < 4 * 3 * NB; i += 256) ((float*)bs)[i] = 0.f;
    __syncthreads();

    const int pz  = t;
    const int izc = (pz < 128) ? pz : 256 - pz;
    const int iz2 = izc * izc;
    const int pzp = (256 - pz) & 255;

    for (int it = 0; it < 64; ++it) {
        int L  = blockIdx.x + 1024 * it;         // interleaved for balance
        int px = L >> 8, py = L & 255;
        int fx = br8(px), fy = br8(py);
        int ax = (fx < 128) ? fx : 256 - fx;
        int ay = (fy < 128) ? fy : 256 - fy;
        int c2 = ax * ax + ay * ay;
        if (c2 >= NB * NB) continue;             // whole line outside sphere (uniform)
        int m  = c2 + iz2;
        int lab = (int)sqrtf((float)m);
        if (lab >= NB) continue;                 // dropped trash bin

        int pxp = br8((256 - fx) & 255);
        int pyp = br8((256 - fy) & 255);
        float2 z1 = A[(long long)L * 256 + pz];
        float2 z2 = A[(long long)(pxp * 256 + pyp) * 256 + pzp];

        float F1r = 0.5f * (z1.x + z2.x);
        float F1i = 0.5f * (z1.y - z2.y);
        float F2r = 0.5f * (z1.y + z2.y);
        float F2i = 0.5f * (z2.x - z1.x);

        atomicAdd(&bs[w][lab],            F1r * F2r + F1i * F2i);  // cross
        atomicAdd(&bs[w][NB + lab],       F1r * F1r + F1i * F1i);  // p1
        atomicAdd(&bs[w][2 * NB + lab],   F2r * F2r + F2i * F2i);  // p2
    }
    __syncthreads();
    for (int i = t; i < 3 * NB; i += 256) {
        float v = bs[0][i] + bs[1][i] + bs[2][i] + bs[3][i];
        atomicAdd(&bins[i], v);
    }
}

// ---------------------------------------------------------------------------
__global__ void zero_bins(float* bins)
{
    int t = blockIdx.x * blockDim.x + threadIdx.x;
    if (t < 2 * 3 * NB) bins[t] = 0.f;
}

__global__ void finalize(const float* __restrict__ binsAll, float* __restrict__ out)
{
    __shared__ float red[256];
    const int t = threadIdx.x;
    const int b = t >> 7, bin = t & 127;
    const float* bb = binsAll + b * 3 * NB;
    float num = bb[bin], d1 = bb[NB + bin], d2 = bb[2 * NB + bin];
    float fsc = num / sqrtf(d1 * d2 + 1e-8f);
    red[t] = fsc * fsc;
    __syncthreads();
    for (int s = 128; s > 0; s >>= 1) {
        if (t < s) red[t] += red[t + s];
        __syncthreads();
    }
    if (t == 0) out[0] = 1.f - red[0] / 256.f;
}

__global__ void ws_too_small(float* out) { out[0] = -1.0e9f; }

// ---------------------------------------------------------------------------
extern "C" void kernel_launch(void* const* d_in, const int* in_sizes, int n_in,
                              void* d_out, int out_size, void* d_ws, size_t ws_size,
                              hipStream_t stream)
{
    const float* ref  = (const float*)d_in[0];
    const float* pred = (const float*)d_in[1];
    float* out = (float*)d_out;

    const size_t volBytes = (size_t)VOL * sizeof(float2);   // 134,217,728
    if (ws_size < volBytes + 4096) {
        ws_too_small<<<1, 1, 0, stream>>>(out);
        return;
    }
    float2* A   = (float2*)d_ws;
    float* bins = (float*)((char*)d_ws + volBytes);          // [2][3][128]

    zero_bins<<<1, 1024, 0, stream>>>(bins);

    for (int b = 0; b < 2; ++b) {
        fftz_pack  <<<16384, 256, 0, stream>>>(ref + (size_t)b * VOL,
                                               pred + (size_t)b * VOL, A);
        fft_strided<<<4096, 256, 0, stream>>>(A, 256,   65536);  // y-pass
        fft_strided<<<4096, 256, 0, stream>>>(A, 65536, 256);    // x-pass
        reduce_shells<<<1024, 256, 0, stream>>>(A, bins + b * 3 * NB);
    }
    finalize<<<1, 256, 0, stream>>>(bins, out);
}

// Round 3
// 730.073 us; speedup vs baseline: 1.4971x; 1.3280x over previous
//
#include <hip/hip_runtime.h>
#include <math.h>

#define NDIM 256
#define VOL  (NDIM*NDIM*NDIM)      // 16777216 elements per batch-channel volume
#define NB   128                    // kept bins 0..127; label 128 is dropped

__device__ __forceinline__ int br8(int x) { return (int)(__brev((unsigned)x) >> 24); }

// ---------------------------------------------------------------------------
// Pass 1: pack (ref + i*pred) and FFT along z (contiguous axis).
// One wave per 256-pt line, radix-2 Stockham in LDS, natural-order output.
// Twiddles from a 128-entry LDS table: angle(k) = -pi*k/128.
// ---------------------------------------------------------------------------
__global__ __launch_bounds__(256) void fftz_pack(const float* __restrict__ re_in,
                                                 const float* __restrict__ im_in,
                                                 float2* __restrict__ out)
{
    __shared__ float2 buf[2][4][NDIM];   // 16 KB
    __shared__ float2 tw[128];           // 1 KB
    const int t = threadIdx.x;
    const int w = t >> 6, lane = t & 63;
    const int L = blockIdx.x * 4 + w;    // line id in [0, 65536)
    const float* rp = re_in + (size_t)L * NDIM;
    const float* ip = im_in + (size_t)L * NDIM;

    if (t < 128) {
        float sn, cs;
        __sincosf(-(float)M_PI * (float)t / 128.0f, &sn, &cs);
        tw[t] = make_float2(cs, sn);
    }
    for (int r = 0; r < 4; ++r) {
        int k = lane + 64 * r;
        buf[0][w][k] = make_float2(rp[k], ip[k]);
    }
    __syncthreads();

    int p = 0;
    for (int st = 0; st < 8; ++st) {
        const int Ns = 1 << st;
        for (int h = 0; h < 2; ++h) {
            int j  = lane + 64 * h;              // butterfly id in [0,128)
            int jm = j & (Ns - 1);
            float2 v0 = buf[p][w][j];
            float2 v1 = buf[p][w][j + 128];
            float2 tt = tw[jm << (7 - st)];
            float2 v1r = make_float2(v1.x * tt.x - v1.y * tt.y,
                                     v1.x * tt.y + v1.y * tt.x);
            int idxD = ((j >> st) << (st + 1)) + jm;
            buf[p ^ 1][w][idxD]      = make_float2(v0.x + v1r.x, v0.y + v1r.y);
            buf[p ^ 1][w][idxD + Ns] = make_float2(v0.x - v1r.x, v0.y - v1r.y);
        }
        __syncthreads();
        p ^= 1;
    }

    float2* op = out + (size_t)L * NDIM;
    for (int r = 0; r < 4; ++r) {
        int k = lane + 64 * r;
        op[k] = buf[p][w][k];
    }
}

// ---------------------------------------------------------------------------
// Passes 2/3: in-place DIF radix-2 FFT along a strided axis.
// Tile: 256 (FFT dim) x 16 (contiguous z) in LDS, ld padded 16->17.
// Output bit-reversed along the transformed axis. Twiddle table in LDS.
// ---------------------------------------------------------------------------
__global__ __launch_bounds__(256) void fft_strided(float2* __restrict__ A,
                                                   int lineStride, int outerStride)
{
    __shared__ float2 tile[NDIM * 17];   // ~34.8 KB
    __shared__ float2 tw[128];
    const int t = threadIdx.x;
    const int l = t & 15, u = t >> 4;
    const int o = blockIdx.x >> 4, c = blockIdx.x & 15;
    const long long base = (long long)o * outerStride + c * 16;

    if (t < 128) {
        float sn, cs;
        __sincosf(-(float)M_PI * (float)t / 128.0f, &sn, &cs);
        tw[t] = make_float2(cs, sn);
    }
    for (int it = 0; it < 16; ++it) {
        int pos = u + it * 16;
        tile[pos * 17 + l] = A[base + (long long)pos * lineStride + l];
    }
    __syncthreads();

    for (int st = 7; st >= 0; --st) {
        const int s = 1 << st;
        for (int it = 0; it < 8; ++it) {
            int m  = u + (it << 4);            // butterfly id in [0,128)
            int jm = m & (s - 1);
            int i0 = ((m >> st) << (st + 1)) + jm;
            int i1 = i0 + s;
            float2 a0 = tile[i0 * 17 + l];
            float2 a1 = tile[i1 * 17 + l];
            tile[i0 * 17 + l] = make_float2(a0.x + a1.x, a0.y + a1.y);
            float dx = a0.x - a1.x, dy = a0.y - a1.y;
            float2 tt = tw[jm << (7 - st)];
            tile[i1 * 17 + l] = make_float2(dx * tt.x - dy * tt.y,
                                            dx * tt.y + dy * tt.x);
        }
        __syncthreads();
    }

    for (int it = 0; it < 16; ++it) {
        int pos = u + it * 16;
        A[base + (long long)pos * lineStride + l] = tile[pos * 17 + l];
    }
}

// ---------------------------------------------------------------------------
// Pass 4: shell reduction, conjugate-pair scheme.
// Each line (px,py) pairs with its -k partner line; F(-k) = conj(F(k)) for
// real inputs, so each pair is processed ONCE with weight 2 (self-paired
// lines: weight 1). Every line is read exactly once -> 134 MB/volume.
// Phase A issues all global loads (up to 16 in flight/thread), phase B
// computes + accumulates into per-wave LDS histograms.
// grid = 8192 blocks x 8 line-jobs; non-canonical jobs skip (uniform).
// ---------------------------------------------------------------------------
__global__ __launch_bounds__(256) void reduce_shells(const float2* __restrict__ A,
                                                     float* __restrict__ bins)
{
    __shared__ float bs[4][3 * NB];      // 6 KB, one histogram per wave
    const int t = threadIdx.x;
    const int w = t >> 6;
    for (int i = t; i < 4 * 3 * NB; i += 256) ((float*)bs)[i] = 0.f;
    __syncthreads();

    const int pz  = t;
    const int izc = (pz < 128) ? pz : 256 - pz;
    const int iz2 = izc * izc;
    const int pzp = (256 - pz) & 255;

    float2 z1[8], z2[8];
    int   lc2[8];     // c2 if job live, else -1
    float wgt[8];

    // ---- phase A: classify jobs, issue loads ----
    #pragma unroll
    for (int jj = 0; jj < 8; ++jj) {
        int L = blockIdx.x * 8 + jj;         // storage-order line id
        int px = L >> 8, py = L & 255;
        int fx = br8(px), fy = br8(py);
        int fxp = (256 - fx) & 255, fyp = (256 - fy) & 255;
        int Lp = br8(fxp) * 256 + br8(fyp);  // partner line (storage order)
        int ax = (fx < 128) ? fx : 256 - fx;
        int ay = (fy < 128) ? fy : 256 - fy;
        int c2 = ax * ax + ay * ay;
        lc2[jj] = -1;
        if (Lp < L) continue;                // partner's block handles this pair
        if (c2 + 1 > NB * NB) continue;      // entire line outside sphere
        lc2[jj] = c2;
        wgt[jj] = (Lp == L) ? 1.f : 2.f;
        z1[jj] = A[(long long)L  * 256 + pz];
        z2[jj] = A[(long long)Lp * 256 + pzp];
    }

    // ---- phase B: unpack + accumulate ----
    #pragma unroll
    for (int jj = 0; jj < 8; ++jj) {
        if (lc2[jj] < 0) continue;
        int m = lc2[jj] + iz2;
        int lab = (int)sqrtf((float)m);
        if (lab >= NB) continue;             // dropped trash bin
        float2 a = z1[jj], b = z2[jj];
        float F1r = 0.5f * (a.x + b.x);
        float F1i = 0.5f * (a.y - b.y);
        float F2r = 0.5f * (a.y + b.y);
        float F2i = 0.5f * (b.x - a.x);
        float g = wgt[jj];
        atomicAdd(&bs[w][lab],           g * (F1r * F2r + F1i * F2i));  // cross
        atomicAdd(&bs[w][NB + lab],      g * (F1r * F1r + F1i * F1i));  // p1
        atomicAdd(&bs[w][2 * NB + lab],  g * (F2r * F2r + F2i * F2i));  // p2
    }
    __syncthreads();
    for (int i = t; i < 3 * NB; i += 256) {
        float v = bs[0][i] + bs[1][i] + bs[2][i] + bs[3][i];
        if (v != 0.f) atomicAdd(&bins[i], v);
    }
}

// ---------------------------------------------------------------------------
__global__ void zero_bins(float* bins)
{
    int t = blockIdx.x * blockDim.x + threadIdx.x;
    if (t < 2 * 3 * NB) bins[t] = 0.f;
}

__global__ void finalize(const float* __restrict__ binsAll, float* __restrict__ out)
{
    __shared__ float red[256];
    const int t = threadIdx.x;
    const int b = t >> 7, bin = t & 127;
    const float* bb = binsAll + b * 3 * NB;
    float num = bb[bin], d1 = bb[NB + bin], d2 = bb[2 * NB + bin];
    float fsc = num / sqrtf(d1 * d2 + 1e-8f);
    red[t] = fsc * fsc;
    __syncthreads();
    for (int s = 128; s > 0; s >>= 1) {
        if (t < s) red[t] += red[t + s];
        __syncthreads();
    }
    if (t == 0) out[0] = 1.f - red[0] / 256.f;
}

__global__ void ws_too_small(float* out) { out[0] = -1.0e9f; }

// ---------------------------------------------------------------------------
extern "C" void kernel_launch(void* const* d_in, const int* in_sizes, int n_in,
                              void* d_out, int out_size, void* d_ws, size_t ws_size,
                              hipStream_t stream)
{
    const float* ref  = (const float*)d_in[0];
    const float* pred = (const float*)d_in[1];
    float* out = (float*)d_out;

    const size_t volBytes = (size_t)VOL * sizeof(float2);   // 134,217,728
    if (ws_size < volBytes + 4096) {
        ws_too_small<<<1, 1, 0, stream>>>(out);
        return;
    }
    float2* A   = (float2*)d_ws;
    float* bins = (float*)((char*)d_ws + volBytes);          // [2][3][128]

    zero_bins<<<1, 1024, 0, stream>>>(bins);

    for (int b = 0; b < 2; ++b) {
        fftz_pack  <<<16384, 256, 0, stream>>>(ref + (size_t)b * VOL,
                                               pred + (size_t)b * VOL, A);
        fft_strided<<<4096, 256, 0, stream>>>(A, 256,   65536);  // y-pass
        fft_strided<<<4096, 256, 0, stream>>>(A, 65536, 256);    // x-pass
        reduce_shells<<<8192, 256, 0, stream>>>(A, bins + b * 3 * NB);
    }
    finalize<<<1, 256, 0, stream>>>(bins, out);
}

// Round 4
// 668.285 us; speedup vs baseline: 1.6355x; 1.0925x over previous
//
#include <hip/hip_runtime.h>
#include <math.h>

#define NDIM 256
#define VOL  (NDIM*NDIM*NDIM)      // 16777216 elements per batch-channel volume
#define NB   128                    // kept bins 0..127; label 128 is dropped

// base-4 digit reversal of an 8-bit index (involution)
__device__ __forceinline__ int dr4(int x) {
    int b = (int)(__brev((unsigned)x) >> 24);
    return ((b >> 1) & 0x55) | ((b << 1) & 0xAA);
}
__device__ __forceinline__ float2 cmul(float2 a, float2 b) {
    return make_float2(a.x * b.x - a.y * b.y, a.x * b.y + a.y * b.x);
}
__device__ __forceinline__ float2 cadd(float2 a, float2 b){ return make_float2(a.x+b.x, a.y+b.y); }
__device__ __forceinline__ float2 csub(float2 a, float2 b){ return make_float2(a.x-b.x, a.y-b.y); }
__device__ __forceinline__ float2 cmuli_neg(float2 a){ return make_float2(a.y, -a.x); }  // -i*a
__device__ __forceinline__ float2 cmuli_pos(float2 a){ return make_float2(-a.y, a.x); }  // +i*a

// ---------------------------------------------------------------------------
// Pass 1: pack (ref + i*pred), radix-4 Stockham FFT along z. One WAVE per
// 256-pt line (wave-private LDS, no barriers). Stage 0 reads global directly;
// stage 3 writes global directly. Natural-order output.
// ---------------------------------------------------------------------------
__global__ __launch_bounds__(256) void fftz_pack(const float* __restrict__ re_in,
                                                 const float* __restrict__ im_in,
                                                 float2* __restrict__ out)
{
    __shared__ float2 buf[4][2][NDIM];   // 16 KB, per-wave double buffer
    const int t = threadIdx.x;
    const int w = t >> 6, j = t & 63;
    const int L = blockIdx.x * 4 + w;    // line id in [0, 65536)
    const float* rp = re_in + (size_t)L * NDIM;
    const float* ip = im_in + (size_t)L * NDIM;

    float2 v0 = make_float2(rp[j      ], ip[j      ]);
    float2 v1 = make_float2(rp[j +  64], ip[j +  64]);
    float2 v2 = make_float2(rp[j + 128], ip[j + 128]);
    float2 v3 = make_float2(rp[j + 192], ip[j + 192]);

    // stage 0 (Ns=1, twiddle = 1): write at 4j + r
    {
        float2 t0=cadd(v0,v2), t1=csub(v0,v2), t2=cadd(v1,v3), t3=csub(v1,v3);
        buf[w][0][4*j    ] = cadd(t0, t2);
        buf[w][0][4*j + 1] = cadd(t1, cmuli_neg(t3));
        buf[w][0][4*j + 2] = csub(t0, t2);
        buf[w][0][4*j + 3] = cadd(t1, cmuli_pos(t3));
    }
    __builtin_amdgcn_sched_barrier(0);

    int p = 0;
    #pragma unroll
    for (int stage = 1; stage <= 2; ++stage) {
        const int Ns = (stage == 1) ? 4 : 16;
        const int jm = j & (Ns - 1);
        float2 a0 = buf[w][p][j      ];
        float2 a1 = buf[w][p][j +  64];
        float2 a2 = buf[w][p][j + 128];
        float2 a3 = buf[w][p][j + 192];
        float sn, cs;
        __sincosf(-(float)(2.0 * M_PI) * (float)jm / (float)(4 * Ns), &sn, &cs);
        float2 w1 = make_float2(cs, sn);
        float2 w2 = cmul(w1, w1);
        float2 w3 = cmul(w2, w1);
        a1 = cmul(a1, w1); a2 = cmul(a2, w2); a3 = cmul(a3, w3);
        float2 t0=cadd(a0,a2), t1=csub(a0,a2), t2=cadd(a1,a3), t3=csub(a1,a3);
        const int idxD = (j / Ns) * (4 * Ns) + jm;
        buf[w][p^1][idxD         ] = cadd(t0, t2);
        buf[w][p^1][idxD +     Ns] = cadd(t1, cmuli_neg(t3));
        buf[w][p^1][idxD + 2 * Ns] = csub(t0, t2);
        buf[w][p^1][idxD + 3 * Ns] = cadd(t1, cmuli_pos(t3));
        p ^= 1;
        __builtin_amdgcn_sched_barrier(0);
    }

    // stage 3 (Ns=64): idxD = j, write straight to global (coalesced runs)
    {
        float2 a0 = buf[w][p][j      ];
        float2 a1 = buf[w][p][j +  64];
        float2 a2 = buf[w][p][j + 128];
        float2 a3 = buf[w][p][j + 192];
        float sn, cs;
        __sincosf(-(float)(2.0 * M_PI) * (float)j / 256.0f, &sn, &cs);
        float2 w1 = make_float2(cs, sn);
        float2 w2 = cmul(w1, w1);
        float2 w3 = cmul(w2, w1);
        a1 = cmul(a1, w1); a2 = cmul(a2, w2); a3 = cmul(a3, w3);
        float2 t0=cadd(a0,a2), t1=csub(a0,a2), t2=cadd(a1,a3), t3=csub(a1,a3);
        float2* op = out + (size_t)L * NDIM;
        op[j      ] = cadd(t0, t2);
        op[j +  64] = cadd(t1, cmuli_neg(t3));
        op[j + 128] = csub(t0, t2);
        op[j + 192] = cadd(t1, cmuli_pos(t3));
    }
}

// ---------------------------------------------------------------------------
// Passes 2/3: in-place radix-4 DIF FFT along a strided axis.
// Tile 256 (FFT dim) x 16 (contiguous z), ld = 18 float2 (16B-aligned pairs).
// float4 global loads/stores. Output base-4 digit-reversed along the axis.
// y-pass: lineStride=256, outerStride=65536; x-pass: 65536 / 256.
// ---------------------------------------------------------------------------
__global__ __launch_bounds__(256) void fft_strided(float2* __restrict__ A,
                                                   int lineStride, int outerStride)
{
    __shared__ float2 tile[NDIM * 18];   // 36.9 KB
    __shared__ float2 tw[NDIM];          // 2 KB: tw[k] = exp(-2*pi*i*k/256)
    const int t = threadIdx.x;
    {
        float sn, cs;
        __sincosf(-(float)(2.0 * M_PI) * (float)t / 256.0f, &sn, &cs);
        tw[t] = make_float2(cs, sn);
    }
    const int l4 = t & 7, u8 = t >> 3;   // load layout: 8 float4 per tile row
    const int o = blockIdx.x >> 4, c = blockIdx.x & 15;
    const long long base = (long long)o * outerStride + c * 16;

    #pragma unroll
    for (int it = 0; it < 8; ++it) {
        int pos = u8 + it * 32;
        const float4 d = *(const float4*)&A[base + (long long)pos * lineStride + 2 * l4];
        tile[pos * 18 + 2 * l4    ] = make_float2(d.x, d.y);
        tile[pos * 18 + 2 * l4 + 1] = make_float2(d.z, d.w);
    }
    __syncthreads();

    const int l = t & 15, u = t >> 4;
    #pragma unroll
    for (int ls = 6; ls >= 0; ls -= 2) {           // s = 64, 16, 4, 1
        const int s = 1 << ls;
        #pragma unroll
        for (int it = 0; it < 4; ++it) {
            int m  = u + it * 16;                  // butterfly id in [0,64)
            int jm = m & (s - 1);
            int bidx = ((m >> ls) << (ls + 2)) + jm;
            float2 a  = tile[(bidx        ) * 18 + l];
            float2 b  = tile[(bidx +     s) * 18 + l];
            float2 cc = tile[(bidx + 2 * s) * 18 + l];
            float2 d  = tile[(bidx + 3 * s) * 18 + l];
            float2 t0=cadd(a,cc), t1=csub(a,cc), t2=cadd(b,d), t3=csub(b,d);
            float2 y0 = cadd(t0, t2);
            float2 y1 = cadd(t1, cmuli_neg(t3));
            float2 y2 = csub(t0, t2);
            float2 y3 = cadd(t1, cmuli_pos(t3));
            int k1 = jm << (6 - ls);               // 256/(4s) multiplier
            y1 = cmul(y1, tw[k1]);
            y2 = cmul(y2, tw[2 * k1]);
            y3 = cmul(y3, tw[3 * k1]);
            tile[(bidx        ) * 18 + l] = y0;
            tile[(bidx +     s) * 18 + l] = y1;
            tile[(bidx + 2 * s) * 18 + l] = y2;
            tile[(bidx + 3 * s) * 18 + l] = y3;
        }
        __syncthreads();
    }

    #pragma unroll
    for (int it = 0; it < 8; ++it) {
        int pos = u8 + it * 32;
        float2 e0 = tile[pos * 18 + 2 * l4], e1 = tile[pos * 18 + 2 * l4 + 1];
        *(float4*)&A[base + (long long)pos * lineStride + 2 * l4] =
            make_float4(e0.x, e0.y, e1.x, e1.y);
    }
}

// ---------------------------------------------------------------------------
// Pass 4: shell reduction, conjugate-pair scheme (each line read once,
// weight 2 for proper pairs). x,y axes are base-4 digit-reversed (dr4),
// z natural. Per-wave LDS histograms; 8192 blocks x 8 line-jobs.
// ---------------------------------------------------------------------------
__global__ __launch_bounds__(256) void reduce_shells(const float2* __restrict__ A,
                                                     float* __restrict__ bins)
{
    __shared__ float bs[4][3 * NB];      // 6 KB, one histogram per wave
    const int t = threadIdx.x;
    const int w = t >> 6;
    for (int i = t; i < 4 * 3 * NB; i += 256) ((float*)bs)[i] = 0.f;
    __syncthreads();

    const int pz  = t;
    const int izc = (pz < 128) ? pz : 256 - pz;
    const int iz2 = izc * izc;
    const int pzp = (256 - pz) & 255;

    float2 z1[8], z2[8];
    int   lc2[8];
    float wgt[8];

    // ---- phase A: classify jobs, issue loads ----
    #pragma unroll
    for (int jj = 0; jj < 8; ++jj) {
        int L = blockIdx.x * 8 + jj;         // storage-order line id
        int px = L >> 8, py = L & 255;
        int fx = dr4(px), fy = dr4(py);
        int fxp = (256 - fx) & 255, fyp = (256 - fy) & 255;
        int Lp = dr4(fxp) * 256 + dr4(fyp);  // partner line (storage order)
        int ax = (fx < 128) ? fx : 256 - fx;
        int ay = (fy < 128) ? fy : 256 - fy;
        int c2 = ax * ax + ay * ay;
        lc2[jj] = -1;
        if (Lp < L) continue;                // partner's block handles this pair
        if (c2 >= NB * NB) continue;         // entire line outside sphere
        lc2[jj] = c2;
        wgt[jj] = (Lp == L) ? 1.f : 2.f;
        z1[jj] = A[(long long)L  * 256 + pz];
        z2[jj] = A[(long long)Lp * 256 + pzp];
    }

    // ---- phase B: unpack + accumulate ----
    #pragma unroll
    for (int jj = 0; jj < 8; ++jj) {
        if (lc2[jj] < 0) continue;
        int m = lc2[jj] + iz2;
        int lab = (int)sqrtf((float)m);
        if (lab >= NB) continue;             // dropped trash bin
        float2 a = z1[jj], b = z2[jj];
        float F1r = 0.5f * (a.x + b.x);
        float F1i = 0.5f * (a.y - b.y);
        float F2r = 0.5f * (a.y + b.y);
        float F2i = 0.5f * (b.x - a.x);
        float g = wgt[jj];
        atomicAdd(&bs[w][lab],           g * (F1r * F2r + F1i * F2i));  // cross
        atomicAdd(&bs[w][NB + lab],      g * (F1r * F1r + F1i * F1i));  // p1
        atomicAdd(&bs[w][2 * NB + lab],  g * (F2r * F2r + F2i * F2i));  // p2
    }
    __syncthreads();
    for (int i = t; i < 3 * NB; i += 256) {
        float v = bs[0][i] + bs[1][i] + bs[2][i] + bs[3][i];
        if (v != 0.f) atomicAdd(&bins[i], v);
    }
}

// ---------------------------------------------------------------------------
__global__ void zero_bins(float* bins)
{
    int t = blockIdx.x * blockDim.x + threadIdx.x;
    if (t < 2 * 3 * NB) bins[t] = 0.f;
}

__global__ void finalize(const float* __restrict__ binsAll, float* __restrict__ out)
{
    __shared__ float red[256];
    const int t = threadIdx.x;
    const int b = t >> 7, bin = t & 127;
    const float* bb = binsAll + b * 3 * NB;
    float num = bb[bin], d1 = bb[NB + bin], d2 = bb[2 * NB + bin];
    float fsc = num / sqrtf(d1 * d2 + 1e-8f);
    red[t] = fsc * fsc;
    __syncthreads();
    for (int s = 128; s > 0; s >>= 1) {
        if (t < s) red[t] += red[t + s];
        __syncthreads();
    }
    if (t == 0) out[0] = 1.f - red[0] / 256.f;
}

__global__ void ws_too_small(float* out) { out[0] = -1.0e9f; }

// ---------------------------------------------------------------------------
extern "C" void kernel_launch(void* const* d_in, const int* in_sizes, int n_in,
                              void* d_out, int out_size, void* d_ws, size_t ws_size,
                              hipStream_t stream)
{
    const float* ref  = (const float*)d_in[0];
    const float* pred = (const float*)d_in[1];
    float* out = (float*)d_out;

    const size_t volBytes = (size_t)VOL * sizeof(float2);   // 134,217,728
    if (ws_size < volBytes + 4096) {
        ws_too_small<<<1, 1, 0, stream>>>(out);
        return;
    }
    float2* A   = (float2*)d_ws;
    float* bins = (float*)((char*)d_ws + volBytes);          // [2][3][128]

    zero_bins<<<1, 1024, 0, stream>>>(bins);

    for (int b = 0; b < 2; ++b) {
        fftz_pack  <<<16384, 256, 0, stream>>>(ref + (size_t)b * VOL,
                                               pred + (size_t)b * VOL, A);
        fft_strided<<<4096, 256, 0, stream>>>(A, 256,   65536);  // y-pass
        fft_strided<<<4096, 256, 0, stream>>>(A, 65536, 256);    // x-pass
        reduce_shells<<<8192, 256, 0, stream>>>(A, bins + b * 3 * NB);
    }
    finalize<<<1, 256, 0, stream>>>(bins, out);
}